// Round 14
// baseline (1234.323 us; speedup 1.0000x reference)
//
#include <hip/hip_runtime.h>

constexpr int N = 30000, E = 480000, G = 128, H = 4, D = 64;
constexpr int NF = 92, EF = 50, GF = 108, L = 5;
constexpr int EQ = E / 4;  // quads per head (120000); slot r -> head r/EQ, quad r%EQ
constexpr float EPS = 1e-3f;

__device__ __forceinline__ float lrelu(float t) { return t > 0.f ? t : 0.2f * t; }

// bf16 helpers (RTN-even), values are finite
__device__ __forceinline__ unsigned short f2bf(float f) {
  unsigned int u = __float_as_uint(f);
  u += 0x7FFFu + ((u >> 16) & 1u);
  return (unsigned short)(u >> 16);
}
__device__ __forceinline__ float bf2f(unsigned short s) {
  return __uint_as_float(((unsigned int)s) << 16);
}

// ---------------- CSR build: slots sorted by row ----------------
__global__ __launch_bounds__(256) void hist_kernel(const int* __restrict__ row,
                                                   int* __restrict__ deg) {
  int e = blockIdx.x * 256 + threadIdx.x;
  atomicAdd(&deg[row[e]], 1);
}

__global__ __launch_bounds__(1024) void scan_kernel(const int* __restrict__ deg,
                                                    int* __restrict__ start) {
  __shared__ int wsum[16];
  __shared__ int cbase;
  if (threadIdx.x == 0) cbase = 0;
  __syncthreads();
  int lane = threadIdx.x & 63, wave = threadIdx.x >> 6;
  for (int base = 0; base < N; base += 1024) {
    int i = base + (int)threadIdx.x;
    int v = (i < N) ? deg[i] : 0;
    int s = v;
#pragma unroll
    for (int off = 1; off < 64; off <<= 1) { int t = __shfl_up(s, off); if (lane >= off) s += t; }
    if (lane == 63) wsum[wave] = s;
    __syncthreads();
    if (wave == 0 && lane < 16) {
      int w = wsum[lane];
#pragma unroll
      for (int off = 1; off < 16; off <<= 1) { int t = __shfl_up(w, off); if (lane >= off) w += t; }
      wsum[lane] = w;
    }
    __syncthreads();
    int wbase = wave ? wsum[wave - 1] : 0;
    if (i < N) start[i] = cbase + wbase + (s - v);
    __syncthreads();
    if (threadIdx.x == 0) cbase += wsum[15];
    __syncthreads();
  }
  if (threadIdx.x == 0) start[N] = cbase;
}

// also emits the inverse permutation spos[slot] = CSR position
__global__ __launch_bounds__(256) void fill_kernel(
    const int* __restrict__ row, const int* __restrict__ start, int* __restrict__ cur,
    int* __restrict__ eid_s, int* __restrict__ spos) {
  int e = blockIdx.x * 256 + threadIdx.x;
  int r = row[e];
  int pos = start[r] + atomicAdd(&cur[r], 1);
  eid_s[pos] = e;
  spos[e] = pos;
}

// head id per CSR position (built once)
__global__ __launch_bounds__(256) void hs8_kernel(const int* __restrict__ eid_s,
                                                  unsigned char* __restrict__ hs8) {
  int p = blockIdx.x * 256 + threadIdx.x;
  if (p < E) hs8[p] = (unsigned char)(eid_s[p] / EQ);
}

// ---------------- graph segment boundaries (batch is sorted) ------------------
__global__ __launch_bounds__(256) void gbound_kernel(const int* __restrict__ batch,
                                                     int* __restrict__ gstart) {
  int n = blockIdx.x * 256 + threadIdx.x;
  if (n >= N) return;
  int b = batch[n];
  int prev = (n == 0) ? -1 : batch[n - 1];
  for (int g = prev + 1; g <= b; g++) gstart[g] = n;
  if (n == N - 1) for (int g = b + 1; g <= G; g++) gstart[g] = N;
}

// ---------------- embedding, double-buffered LDS staging ----------------
template <int K, bool BF16OUT>
__global__ __launch_bounds__(256) void embed7_kernel(
    const float* __restrict__ in, const float* __restrict__ W,
    const float* __restrict__ bias, float* __restrict__ outF,
    unsigned short* __restrict__ outB, int ntiles) {
  constexpr int KP = (K + 3) & ~3;
  constexpr int NL = (16 * K + 255) / 256;
  __shared__ float xs[2][16][KP];
  int tid = threadIdx.x, lane = tid & 63, wave = tid >> 6;
  if (K != KP) {
    for (int f = tid; f < 2 * 16 * KP; f += 256)
      if (f % KP >= K) ((float*)xs)[f] = 0.f;
  }
  float wreg[KP];
#pragma unroll
  for (int k = 0; k < K; k++) wreg[k] = W[k * 64 + lane];
#pragma unroll
  for (int k = K; k < KP; k++) wreg[k] = 0.f;
  float bb = bias[lane];
  float stage[NL];
  int t = blockIdx.x;
  if (t < ntiles) {
#pragma unroll
    for (int i = 0; i < NL; i++) { int f = tid + i * 256; if (f < 16 * K) stage[i] = in[(size_t)t * 16 * K + f]; }
#pragma unroll
    for (int i = 0; i < NL; i++) { int f = tid + i * 256; if (f < 16 * K) xs[0][f / K][f % K] = stage[i]; }
  }
  __syncthreads();
  int cur = 0;
  for (; t < ntiles; t += gridDim.x) {
    int nxt = t + gridDim.x;
    if (nxt < ntiles) {
#pragma unroll
      for (int i = 0; i < NL; i++) { int f = tid + i * 256; if (f < 16 * K) stage[i] = in[(size_t)nxt * 16 * K + f]; }
    }
    float a0 = 0.f, a1 = 0.f, a2 = 0.f, a3 = 0.f;
#pragma unroll
    for (int kc = 0; kc < KP / 4; kc++) {
      float4 x0 = *(const float4*)&xs[cur][wave * 4 + 0][kc * 4];
      float4 x1 = *(const float4*)&xs[cur][wave * 4 + 1][kc * 4];
      float4 x2 = *(const float4*)&xs[cur][wave * 4 + 2][kc * 4];
      float4 x3 = *(const float4*)&xs[cur][wave * 4 + 3][kc * 4];
      float w0 = wreg[kc * 4], w1 = wreg[kc * 4 + 1], w2 = wreg[kc * 4 + 2], w3 = wreg[kc * 4 + 3];
      a0 = fmaf(x0.x, w0, fmaf(x0.y, w1, fmaf(x0.z, w2, fmaf(x0.w, w3, a0))));
      a1 = fmaf(x1.x, w0, fmaf(x1.y, w1, fmaf(x1.z, w2, fmaf(x1.w, w3, a1))));
      a2 = fmaf(x2.x, w0, fmaf(x2.y, w1, fmaf(x2.z, w2, fmaf(x2.w, w3, a2))));
      a3 = fmaf(x3.x, w0, fmaf(x3.y, w1, fmaf(x3.z, w2, fmaf(x3.w, w3, a3))));
    }
    size_t o = ((size_t)t * 16 + wave * 4) * 64 + lane;
    float r0 = lrelu(a0 + bb), r1 = lrelu(a1 + bb), r2 = lrelu(a2 + bb), r3 = lrelu(a3 + bb);
    if (BF16OUT) {
      outB[o] = f2bf(r0); outB[o + 64] = f2bf(r1);
      outB[o + 128] = f2bf(r2); outB[o + 192] = f2bf(r3);
    } else {
      outF[o] = r0; outF[o + 64] = r1; outF[o + 128] = r2; outF[o + 192] = r3;
    }
    if (nxt < ntiles) {
#pragma unroll
      for (int i = 0; i < NL; i++) { int f = tid + i * 256; if (f < 16 * K) xs[cur ^ 1][f / K][f % K] = stage[i]; }
    }
    __syncthreads();
    cur ^= 1;
  }
}

// ---------------- all-layer tiny precompute ----------------
__global__ __launch_bounds__(256) void aes_watt_all_kernel(
    const float* __restrict__ conv_W, const float* __restrict__ conv_att,
    float* __restrict__ AesT, float* __restrict__ WattT) {
  int l = blockIdx.x;
  const float* W = conv_W + (size_t)l * 128 * 256;
  const float* att = conv_att + (size_t)l * H * 128;
  int t = threadIdx.x;
  {
    int h = t >> 6, k = t & 63;
    float acc = 0.f;
    for (int d = 0; d < 64; d++)
      acc = fmaf(W[(64 + k) * 256 + h * 64 + d], att[h * 128 + d] + att[h * 128 + 64 + d], acc);
    AesT[l * 256 + h * 64 + k] = acc;
  }
  for (int idx = t; idx < 512; idx += 256) {
    int hh = idx >> 6, k = idx & 63;
    int h = hh >> 1, ij = hh & 1;
    float acc = 0.f;
    for (int d = 0; d < 64; d++)
      acc = fmaf(W[k * 256 + h * 64 + d], att[h * 128 + ij * 64 + d], acc);
    WattT[l * 512 + idx] = acc;
  }
}

// ---------------- qs3: block owns layer l; AesT in regs; stream edges --------
constexpr int QS_CPL = 960;  // chunks-per-layer stride
__global__ __launch_bounds__(256) void qs3_kernel(
    const unsigned short* __restrict__ ea, const float* __restrict__ AesT,
    float* __restrict__ qsAll) {
  int l = blockIdx.x / QS_CPL;
  int bx = blockIdx.x % QS_CPL;
  int tid = threadIdx.x;
  int k16 = tid & 3;
  float A[4][16];
#pragma unroll
  for (int h = 0; h < 4; h++) {
    const float* Ap = &AesT[l * 256 + h * 64 + k16 * 16];
#pragma unroll
    for (int j4 = 0; j4 < 4; j4++) {
      float4 v = ((const float4*)Ap)[j4];
      A[h][4 * j4] = v.x; A[h][4 * j4 + 1] = v.y;
      A[h][4 * j4 + 2] = v.z; A[h][4 * j4 + 3] = v.w;
    }
  }
  float* qOut = qsAll + (size_t)l * E * 4;
  for (int c = bx; c < E / 64; c += QS_CPL) {
    int e = c * 64 + (tid >> 2);
    const uint4* base = (const uint4*)&ea[(size_t)e * 64 + k16 * 16];
    uint4 ra = base[0], rb = base[1];
    float xv[16];
    {
      unsigned int uu[8] = {ra.x, ra.y, ra.z, ra.w, rb.x, rb.y, rb.z, rb.w};
#pragma unroll
      for (int i = 0; i < 8; i++) {
        xv[2 * i]     = __uint_as_float(uu[i] << 16);
        xv[2 * i + 1] = __uint_as_float(uu[i] & 0xFFFF0000u);
      }
    }
    float q0 = 0.f, q1 = 0.f, q2 = 0.f, q3 = 0.f;
#pragma unroll
    for (int j = 0; j < 16; j++) {
      float x = xv[j];
      q0 = fmaf(x, A[0][j], q0);
      q1 = fmaf(x, A[1][j], q1);
      q2 = fmaf(x, A[2][j], q2);
      q3 = fmaf(x, A[3][j], q3);
    }
    q0 += __shfl_xor(q0, 1); q1 += __shfl_xor(q1, 1);
    q2 += __shfl_xor(q2, 1); q3 += __shfl_xor(q3, 1);
    q0 += __shfl_xor(q0, 2); q1 += __shfl_xor(q1, 2);
    q2 += __shfl_xor(q2, 2); q3 += __shfl_xor(q3, 2);
    float qv = (k16 == 0) ? q0 : (k16 == 1) ? q1 : (k16 == 2) ? q2 : q3;
    qOut[(size_t)e * 4 + k16] = qv;
  }
}

// ---------------- xW = x@W[0:64,:] -> bf16 head-major [h][n][64]; + pi/pj -----
__global__ __launch_bounds__(256) void xw_kernel(
    const float* __restrict__ xc, const float* __restrict__ W, const float* __restrict__ WattT,
    unsigned short* __restrict__ xWh, float* __restrict__ pi, float* __restrict__ pj) {
  __shared__ float xs[16][64];
  __shared__ float wlT[8][68];
  int tid = threadIdx.x, blk = blockIdx.x, n0 = blk * 16;
  for (int f = tid; f < 1024; f += 256) xs[f >> 6][f & 63] = xc[(size_t)n0 * 64 + f];
  for (int f = tid; f < 512; f += 256) wlT[f >> 6][f & 63] = WattT[f];
  __syncthreads();
  float acc[16];
#pragma unroll
  for (int n = 0; n < 16; n++) acc[n] = 0.f;
#pragma unroll 4
  for (int kc = 0; kc < 16; kc++) {
    float w0 = W[(4 * kc + 0) * 256 + tid];
    float w1 = W[(4 * kc + 1) * 256 + tid];
    float w2 = W[(4 * kc + 2) * 256 + tid];
    float w3 = W[(4 * kc + 3) * 256 + tid];
#pragma unroll
    for (int n = 0; n < 16; n++) {
      float4 xv = *(const float4*)&xs[n][4 * kc];
      acc[n] = fmaf(xv.x, w0, fmaf(xv.y, w1, fmaf(xv.z, w2, fmaf(xv.w, w3, acc[n]))));
    }
  }
  int h = tid >> 6, dd = tid & 63;
#pragma unroll
  for (int n = 0; n < 16; n++)
    xWh[((size_t)h * N + (n0 + n)) * 64 + dd] = f2bf(acc[n]);
  if (tid < 128) {
    int n = tid >> 3, hh = tid & 7;
    float a = 0.f;
#pragma unroll
    for (int kc = 0; kc < 16; kc++) {
      float4 xv = *(const float4*)&xs[n][4 * kc];
      float4 wv = *(const float4*)&wlT[hh][4 * kc];
      a = fmaf(xv.x, wv.x, fmaf(xv.y, wv.y, fmaf(xv.z, wv.z, fmaf(xv.w, wv.w, a))));
    }
    int hq = hh >> 1, ij = hh & 1;
    float* dst = ij ? pj : pi;
    dst[(n0 + n) * 4 + hq] = a;
  }
}

// ---------------- edge scores: 1 thread/edge, reads precomputed qs ------------
__global__ __launch_bounds__(256) void score2_kernel(
    const float* __restrict__ qs, const float* __restrict__ pi, const float* __restrict__ pj,
    const int* __restrict__ row, const int* __restrict__ col,
    const float* __restrict__ bng, const float* __restrict__ bnb,
    const float* __restrict__ bnm, const float* __restrict__ bnv,
    float* __restrict__ aArr) {
  int e = blockIdx.x * 256 + threadIdx.x;
  int r = row[e], c = col[e];
  float4 q = ((const float4*)qs)[e];
  float4 piv = ((const float4*)pi)[r];
  float4 pjv = ((const float4*)pj)[c];
  float A0 = bng[0] * rsqrtf(bnv[0] + EPS), B0 = bnb[0] - bnm[0] * A0;
  float A1 = bng[1] * rsqrtf(bnv[1] + EPS), B1 = bnb[1] - bnm[1] * A1;
  float A2 = bng[2] * rsqrtf(bnv[2] + EPS), B2 = bnb[2] - bnm[2] * A2;
  float A3 = bng[3] * rsqrtf(bnv[3] + EPS), B3 = bnb[3] - bnm[3] * A3;
  float4 out;
  out.x = expf(lrelu(piv.x + pjv.x + q.x) * A0 + B0);
  out.y = expf(lrelu(piv.y + pjv.y + q.y) * A1 + B1);
  out.z = expf(lrelu(piv.z + pjv.z + q.z) * A2 + B2);
  out.w = expf(lrelu(piv.w + pjv.w + q.w) * A3 + B3);
  ((float4*)aArr)[e] = out;
}

// ---------------- softmax denom per (node,h) via CSR, no atomics --------------
__global__ __launch_bounds__(256) void normsum_kernel(
    const float* __restrict__ aArr, const int* __restrict__ start,
    const int* __restrict__ eid_s, float* __restrict__ inv) {
  int n = blockIdx.x * 256 + threadIdx.x;
  if (n >= N) return;
  int s0 = start[n], s1 = start[n + 1];
  float4 s = {0.f, 0.f, 0.f, 0.f};
  int p = s0;
  for (; p + 4 <= s1; p += 4) {
    int e0 = eid_s[p], e1 = eid_s[p + 1], e2 = eid_s[p + 2], e3 = eid_s[p + 3];
    float4 a0 = ((const float4*)aArr)[e0];
    float4 a1 = ((const float4*)aArr)[e1];
    float4 a2 = ((const float4*)aArr)[e2];
    float4 a3 = ((const float4*)aArr)[e3];
    s.x += (a0.x + a1.x) + (a2.x + a3.x);
    s.y += (a0.y + a1.y) + (a2.y + a3.y);
    s.z += (a0.z + a1.z) + (a2.z + a3.z);
    s.w += (a0.w + a1.w) + (a2.w + a3.w);
  }
  for (; p < s1; p++) {
    float4 a = ((const float4*)aArr)[eid_s[p]];
    s.x += a.x; s.y += a.y; s.z += a.z; s.w += a.w;
  }
  float4 iv;
  if (s1 > s0) { iv.x = 1.f / s.x; iv.y = 1.f / s.y; iv.z = 1.f / s.z; iv.w = 1.f / s.w; }
  else         { iv.x = iv.y = iv.z = iv.w = 0.f; }
  ((float4*)inv)[n] = iv;
}

// ---------------- zyquad: per quad q, all 4 heads; writes to CSR position -----
// ZYperm[p][0..63] = Z row, [64..127] = Y row, p = spos[slot r]
__global__ __launch_bounds__(256) void zyquad_kernel(
    const float* __restrict__ aArr, const float* __restrict__ invA,
    const unsigned short* __restrict__ ea, const unsigned short* __restrict__ xWh,
    const int* __restrict__ row, const int* __restrict__ col,
    const int* __restrict__ spos, unsigned short* __restrict__ ZYperm) {
  int q = blockIdx.x * 4 + (threadIdx.x >> 6);
  int lane = threadIdx.x & 63;
  const unsigned short* er = ea + (size_t)q * 256 + lane;
  float e0 = bf2f(er[0]), e1 = bf2f(er[64]), e2 = bf2f(er[128]), e3 = bf2f(er[192]);
  int4 rw = *(const int4*)&row[4 * q];
  int4 cl = *(const int4*)&col[4 * q];
  float4 A0 = ((const float4*)aArr)[4 * q + 0];
  float4 A1 = ((const float4*)aArr)[4 * q + 1];
  float4 A2 = ((const float4*)aArr)[4 * q + 2];
  float4 A3 = ((const float4*)aArr)[4 * q + 3];
  float4 I0 = ((const float4*)invA)[rw.x];
  float4 I1 = ((const float4*)invA)[rw.y];
  float4 I2 = ((const float4*)invA)[rw.z];
  float4 I3 = ((const float4*)invA)[rw.w];
  float c0[4] = {A0.x * I0.x, A0.y * I0.y, A0.z * I0.z, A0.w * I0.w};
  float c1[4] = {A1.x * I1.x, A1.y * I1.y, A1.z * I1.z, A1.w * I1.w};
  float c2[4] = {A2.x * I2.x, A2.y * I2.y, A2.z * I2.z, A2.w * I2.w};
  float c3[4] = {A3.x * I3.x, A3.y * I3.y, A3.z * I3.z, A3.w * I3.w};
#pragma unroll
  for (int h = 0; h < 4; h++) {
    const unsigned short* xw = xWh + (size_t)h * N * 64 + lane;
    float g0 = bf2f(xw[(size_t)cl.x * 64]);
    float g1 = bf2f(xw[(size_t)cl.y * 64]);
    float g2 = bf2f(xw[(size_t)cl.z * 64]);
    float g3 = bf2f(xw[(size_t)cl.w * 64]);
    float y = fmaf(c0[h], e0, fmaf(c1[h], e1, fmaf(c2[h], e2, c3[h] * e3)));
    float z = fmaf(c0[h], g0, fmaf(c1[h], g1, fmaf(c2[h], g2, c3[h] * g3)));
    size_t p = (size_t)spos[h * EQ + q];
    ZYperm[p * 128 + lane] = f2bf(z);
    ZYperm[p * 128 + 64 + lane] = f2bf(y);
  }
}

// ---------------- scatter3: wave per node, SEQUENTIAL ZY rows -----------------
__global__ __launch_bounds__(256) void scatter3_kernel(
    const unsigned short* __restrict__ ZYperm, const unsigned char* __restrict__ hs8,
    const int* __restrict__ start,
    float* __restrict__ out1, float* __restrict__ Bacc) {
  int wave = threadIdx.x >> 6, lane = threadIdx.x & 63;
  int n = blockIdx.x * 4 + wave;
  int s0 = __builtin_amdgcn_readfirstlane(start[n]);
  int s1 = __builtin_amdgcn_readfirstlane(start[n + 1]);
  float m = 0.f;
  float b0 = 0.f, b1 = 0.f, b2 = 0.f, b3 = 0.f;
  int p = s0;
  for (; p + 4 <= s1; p += 4) {
    const unsigned short* zy = ZYperm + (size_t)p * 128;
    float z0 = bf2f(zy[lane]),        y0 = bf2f(zy[64 + lane]);
    float z1 = bf2f(zy[128 + lane]),  y1 = bf2f(zy[192 + lane]);
    float z2 = bf2f(zy[256 + lane]),  y2 = bf2f(zy[320 + lane]);
    float z3 = bf2f(zy[384 + lane]),  y3 = bf2f(zy[448 + lane]);
    int h0 = hs8[p], h1 = hs8[p + 1], h2 = hs8[p + 2], h3 = hs8[p + 3];
    m += (z0 + z1) + (z2 + z3);
    if (h0 == 0) b0 += y0; else if (h0 == 1) b1 += y0; else if (h0 == 2) b2 += y0; else b3 += y0;
    if (h1 == 0) b0 += y1; else if (h1 == 1) b1 += y1; else if (h1 == 2) b2 += y1; else b3 += y1;
    if (h2 == 0) b0 += y2; else if (h2 == 1) b1 += y2; else if (h2 == 2) b2 += y2; else b3 += y2;
    if (h3 == 0) b0 += y3; else if (h3 == 1) b1 += y3; else if (h3 == 2) b2 += y3; else b3 += y3;
  }
  for (; p < s1; p++) {
    const unsigned short* zy = ZYperm + (size_t)p * 128;
    float z = bf2f(zy[lane]), y = bf2f(zy[64 + lane]);
    m += z;
    int h = hs8[p];
    if (h == 0) b0 += y; else if (h == 1) b1 += y; else if (h == 2) b2 += y; else b3 += y;
  }
  out1[(size_t)n * 64 + lane] = m;
  float* Bn = Bacc + (size_t)n * 256 + lane;
  Bn[0] = b0; Bn[64] = b1; Bn[128] = b2; Bn[192] = b3;
}

// ---------------- finish: x += bias + 0.25*(out1 + B@W_e) ----------------
__global__ __launch_bounds__(256) void finish_kernel(
    const float* __restrict__ out1, const float* __restrict__ Bacc,
    const float* __restrict__ W, const float* __restrict__ bias, float* __restrict__ xc) {
  __shared__ float Bl[16][256];
  int tid = threadIdx.x, blk = blockIdx.x;
  for (int f = tid; f < 4096; f += 256) Bl[f >> 8][f & 255] = Bacc[(size_t)blk * 4096 + f];
  __syncthreads();
  int lane = tid & 63, wave = tid >> 6;
  float a0 = 0.f, a1 = 0.f, a2 = 0.f, a3 = 0.f;
#pragma unroll
  for (int h = 0; h < 4; h++) {
#pragma unroll 4
    for (int kc = 0; kc < 16; kc++) {
      float w0 = W[(64 + 4 * kc + 0) * 256 + h * 64 + lane];
      float w1 = W[(64 + 4 * kc + 1) * 256 + h * 64 + lane];
      float w2 = W[(64 + 4 * kc + 2) * 256 + h * 64 + lane];
      float w3 = W[(64 + 4 * kc + 3) * 256 + h * 64 + lane];
      float4 b0v = *(const float4*)&Bl[wave * 4 + 0][h * 64 + 4 * kc];
      float4 b1v = *(const float4*)&Bl[wave * 4 + 1][h * 64 + 4 * kc];
      float4 b2v = *(const float4*)&Bl[wave * 4 + 2][h * 64 + 4 * kc];
      float4 b3v = *(const float4*)&Bl[wave * 4 + 3][h * 64 + 4 * kc];
      a0 = fmaf(b0v.x, w0, fmaf(b0v.y, w1, fmaf(b0v.z, w2, fmaf(b0v.w, w3, a0))));
      a1 = fmaf(b1v.x, w0, fmaf(b1v.y, w1, fmaf(b1v.z, w2, fmaf(b1v.w, w3, a1))));
      a2 = fmaf(b2v.x, w0, fmaf(b2v.y, w1, fmaf(b2v.z, w2, fmaf(b2v.w, w3, a2))));
      a3 = fmaf(b3v.x, w0, fmaf(b3v.y, w1, fmaf(b3v.z, w2, fmaf(b3v.w, w3, a3))));
    }
  }
  float bb = bias[lane];
  size_t i0 = (size_t)(blk * 16 + wave * 4) * 64 + lane;
  xc[i0]       += bb + 0.25f * (out1[i0] + a0);
  xc[i0 + 64]  += bb + 0.25f * (out1[i0 + 64] + a1);
  xc[i0 + 128] += bb + 0.25f * (out1[i0 + 128] + a2);
  xc[i0 + 192] += bb + 0.25f * (out1[i0 + 192] + a3);
}

// ---------------- global attention, stage 0 precompute ----------------
__global__ __launch_bounds__(256) void gacontrib_kernel(
    const float* __restrict__ gfeat, const float* __restrict__ W0,
    const float* __restrict__ b0, float* __restrict__ gc) {
  __shared__ float gs[16][GF];
  int tid = threadIdx.x, blk = blockIdx.x;
  int lane = tid & 63, wave = tid >> 6;
  for (int f = tid; f < 16 * GF; f += 256) gs[f / GF][f % GF] = gfeat[(size_t)blk * 16 * GF + f];
  float wreg[GF];
#pragma unroll
  for (int k = 0; k < GF; k++) wreg[k] = W0[(64 + k) * 64 + lane];
  __syncthreads();
  float a0 = 0.f, a1 = 0.f, a2 = 0.f, a3 = 0.f;
#pragma unroll
  for (int kc = 0; kc < GF / 4; kc++) {
    float4 x0 = *(const float4*)&gs[wave * 4 + 0][kc * 4];
    float4 x1 = *(const float4*)&gs[wave * 4 + 1][kc * 4];
    float4 x2 = *(const float4*)&gs[wave * 4 + 2][kc * 4];
    float4 x3 = *(const float4*)&gs[wave * 4 + 3][kc * 4];
    float w0 = wreg[kc * 4], w1 = wreg[kc * 4 + 1], w2 = wreg[kc * 4 + 2], w3 = wreg[kc * 4 + 3];
    a0 = fmaf(x0.x, w0, fmaf(x0.y, w1, fmaf(x0.z, w2, fmaf(x0.w, w3, a0))));
    a1 = fmaf(x1.x, w0, fmaf(x1.y, w1, fmaf(x1.z, w2, fmaf(x1.w, w3, a1))));
    a2 = fmaf(x2.x, w0, fmaf(x2.y, w1, fmaf(x2.z, w2, fmaf(x2.w, w3, a2))));
    a3 = fmaf(x3.x, w0, fmaf(x3.y, w1, fmaf(x3.z, w2, fmaf(x3.w, w3, a3))));
  }
  float bb = b0[lane];
  size_t o = ((size_t)blk * 16 + wave * 4) * 64 + lane;
  gc[o]       = a0 + bb;
  gc[o + 64]  = a1 + bb;
  gc[o + 128] = a2 + bb;
  gc[o + 192] = a3 + bb;
}

// ---------------- ga stage 1 ----------------
__global__ __launch_bounds__(256) void ga0_kernel(
    const float* __restrict__ xc, const float* __restrict__ gc, const int* __restrict__ batch,
    const float* __restrict__ W0,
    const float* __restrict__ g0, const float* __restrict__ bb0,
    const float* __restrict__ m0, const float* __restrict__ v0,
    float* __restrict__ hout, int ntiles) {
  __shared__ float xs[16][64];
  __shared__ int bl[16];
  int tid = threadIdx.x, lane = tid & 63, wave = tid >> 6;
  float wreg[64];
#pragma unroll
  for (int k = 0; k < 64; k++) wreg[k] = W0[k * 64 + lane];
  float sc = rsqrtf(v0[lane] + EPS) * g0[lane];
  float mm = m0[lane], be = bb0[lane];
  for (int t = blockIdx.x; t < ntiles; t += gridDim.x) {
    __syncthreads();
    if (tid < 16) bl[tid] = batch[t * 16 + tid];
    for (int f = tid; f < 1024; f += 256) xs[f >> 6][f & 63] = xc[(size_t)t * 1024 + f];
    __syncthreads();
    float a0 = 0.f, a1 = 0.f, a2 = 0.f, a3 = 0.f;
#pragma unroll
    for (int kc = 0; kc < 16; kc++) {
      float4 x0 = *(const float4*)&xs[wave * 4 + 0][kc * 4];
      float4 x1 = *(const float4*)&xs[wave * 4 + 1][kc * 4];
      float4 x2 = *(const float4*)&xs[wave * 4 + 2][kc * 4];
      float4 x3 = *(const float4*)&xs[wave * 4 + 3][kc * 4];
      float w0 = wreg[kc * 4], w1 = wreg[kc * 4 + 1], w2 = wreg[kc * 4 + 2], w3 = wreg[kc * 4 + 3];
      a0 = fmaf(x0.x, w0, fmaf(x0.y, w1, fmaf(x0.z, w2, fmaf(x0.w, w3, a0))));
      a1 = fmaf(x1.x, w0, fmaf(x1.y, w1, fmaf(x1.z, w2, fmaf(x1.w, w3, a1))));
      a2 = fmaf(x2.x, w0, fmaf(x2.y, w1, fmaf(x2.z, w2, fmaf(x2.w, w3, a2))));
      a3 = fmaf(x3.x, w0, fmaf(x3.y, w1, fmaf(x3.z, w2, fmaf(x3.w, w3, a3))));
    }
    a0 += gc[(size_t)bl[wave * 4 + 0] * 64 + lane];
    a1 += gc[(size_t)bl[wave * 4 + 1] * 64 + lane];
    a2 += gc[(size_t)bl[wave * 4 + 2] * 64 + lane];
    a3 += gc[(size_t)bl[wave * 4 + 3] * 64 + lane];
    size_t o = ((size_t)t * 16 + wave * 4) * 64 + lane;
    hout[o]       = fmaxf((a0 - mm) * sc + be, 0.f);
    hout[o + 64]  = fmaxf((a1 - mm) * sc + be, 0.f);
    hout[o + 128] = fmaxf((a2 - mm) * sc + be, 0.f);
    hout[o + 192] = fmaxf((a3 - mm) * sc + be, 0.f);
  }
}

// ---------------- ga stage 2: a_un only, NO atomics ----------------
__global__ __launch_bounds__(256) void ga1_kernel(
    const float* __restrict__ hbuf,
    const float* __restrict__ W1, const float* __restrict__ b1,
    const float* __restrict__ g1, const float* __restrict__ bb1,
    const float* __restrict__ m1, const float* __restrict__ v1,
    const float* __restrict__ W2, const float* __restrict__ b2,
    float* __restrict__ a_un, int ntiles) {
  __shared__ float hsh[16][64];
  int tid = threadIdx.x, lane = tid & 63, wave = tid >> 6;
  float wreg[64];
#pragma unroll
  for (int k = 0; k < 64; k++) wreg[k] = W1[k * 64 + lane];
  float sc1 = rsqrtf(v1[lane] + EPS) * g1[lane];
  float mm1 = m1[lane], be1 = bb1[lane], bb1v = b1[lane];
  float w2v = W2[lane], b2v = b2[0];
  for (int t = blockIdx.x; t < ntiles; t += gridDim.x) {
    __syncthreads();
    for (int f = tid; f < 1024; f += 256) hsh[f >> 6][f & 63] = hbuf[(size_t)t * 1024 + f];
    __syncthreads();
    float c0 = 0.f, c1 = 0.f, c2 = 0.f, c3 = 0.f;
#pragma unroll
    for (int kc = 0; kc < 16; kc++) {
      float4 x0 = *(const float4*)&hsh[wave * 4 + 0][kc * 4];
      float4 x1 = *(const float4*)&hsh[wave * 4 + 1][kc * 4];
      float4 x2 = *(const float4*)&hsh[wave * 4 + 2][kc * 4];
      float4 x3 = *(const float4*)&hsh[wave * 4 + 3][kc * 4];
      float w0 = wreg[kc * 4], w1 = wreg[kc * 4 + 1], w2 = wreg[kc * 4 + 2], w3 = wreg[kc * 4 + 3];
      c0 = fmaf(x0.x, w0, fmaf(x0.y, w1, fmaf(x0.z, w2, fmaf(x0.w, w3, c0))));
      c1 = fmaf(x1.x, w0, fmaf(x1.y, w1, fmaf(x1.z, w2, fmaf(x1.w, w3, c1))));
      c2 = fmaf(x2.x, w0, fmaf(x2.y, w1, fmaf(x2.z, w2, fmaf(x2.w, w3, c2))));
      c3 = fmaf(x3.x, w0, fmaf(x3.y, w1, fmaf(x3.z, w2, fmaf(x3.w, w3, c3))));
    }
    float p0 = fmaxf((c0 + bb1v - mm1) * sc1 + be1, 0.f) * w2v;
    float p1 = fmaxf((c1 + bb1v - mm1) * sc1 + be1, 0.f) * w2v;
    float p2 = fmaxf((c2 + bb1v - mm1) * sc1 + be1, 0.f) * w2v;
    float p3 = fmaxf((c3 + bb1v - mm1) * sc1 + be1, 0.f) * w2v;
#pragma unroll
    for (int off = 1; off < 64; off <<= 1) {
      p0 += __shfl_xor(p0, off); p1 += __shfl_xor(p1, off);
      p2 += __shfl_xor(p2, off); p3 += __shfl_xor(p3, off);
    }
    if (lane < 4) {
      float pv = (lane == 0) ? p0 : (lane == 1) ? p1 : (lane == 2) ? p2 : p3;
      a_un[t * 16 + wave * 4 + lane] = expf(pv + b2v);
    }
  }
}

// ---------------- pool2: block per graph, segment reduce, no atomics ----------
__global__ __launch_bounds__(256) void pool2_kernel(
    const float* __restrict__ xc, const float* __restrict__ a_un,
    const int* __restrict__ gstart, float* __restrict__ pooled) {
  __shared__ float red[4][64];
  __shared__ float s_norm;
  int g = blockIdx.x;
  int tid = threadIdx.x, lane = tid & 63, wave = tid >> 6;
  int s0 = gstart[g], s1 = gstart[g + 1];
  float ns = 0.f;
  for (int n = s0 + tid; n < s1; n += 256) ns += a_un[n];
#pragma unroll
  for (int off = 1; off < 64; off <<= 1) ns += __shfl_xor(ns, off);
  if (lane == 0) red[wave][0] = ns;
  __syncthreads();
  if (tid == 0) s_norm = (red[0][0] + red[1][0]) + (red[2][0] + red[3][0]);
  __syncthreads();
  float inv = (s1 > s0) ? 1.f / s_norm : 0.f;
  __syncthreads();
  float acc = 0.f;
  for (int n = s0 + wave; n < s1; n += 4)
    acc = fmaf(xc[(size_t)n * 64 + lane], a_un[n], acc);
  red[wave][lane] = acc;
  __syncthreads();
  if (wave == 0)
    pooled[(size_t)g * 64 + lane] =
        inv * ((red[0][lane] + red[1][lane]) + (red[2][lane] + red[3][lane]));
}

__global__ __launch_bounds__(256) void final_kernel(
    const float* __restrict__ pooled, const float* __restrict__ W0,
    const float* __restrict__ b0, const float* __restrict__ W1,
    const float* __restrict__ b1, float* __restrict__ out) {
  int g = blockIdx.x * 4 + (threadIdx.x >> 6);
  int d = threadIdx.x & 63;
  float pv = pooled[g * 64 + d];
  float acc = b0[d];
  for (int k = 0; k < 64; k++) acc = fmaf(__shfl(pv, k), W0[k * 64 + d], acc);
  acc = fmaxf(acc, 0.f);
  float p = acc * W1[d];
  for (int off = 1; off < 64; off <<= 1) p += __shfl_xor(p, off);
  if (d == 0) out[g] = p + b1[0];
}

extern "C" void kernel_launch(void* const* d_in, const int* in_sizes, int n_in,
                              void* d_out, int out_size, void* d_ws, size_t ws_size,
                              hipStream_t stream) {
  (void)in_sizes; (void)n_in; (void)out_size; (void)ws_size;
  const float* x_in    = (const float*)d_in[0];
  const float* ea_in   = (const float*)d_in[1];
  const float* gf      = (const float*)d_in[2];
  const float* node_W  = (const float*)d_in[3];
  const float* node_b  = (const float*)d_in[4];
  const float* edge_W  = (const float*)d_in[5];
  const float* edge_b  = (const float*)d_in[6];
  const float* conv_W  = (const float*)d_in[7];
  const float* conv_att= (const float*)d_in[8];
  const float* conv_bias=(const float*)d_in[9];
  const float* bn_g = (const float*)d_in[10];
  const float* bn_b = (const float*)d_in[11];
  const float* bn_m = (const float*)d_in[12];
  const float* bn_v = (const float*)d_in[13];
  const float* ga_W0 = (const float*)d_in[14]; const float* ga_b0 = (const float*)d_in[15];
  const float* ga0g = (const float*)d_in[16];  const float* ga0b = (const float*)d_in[17];
  const float* ga0m = (const float*)d_in[18];  const float* ga0v = (const float*)d_in[19];
  const float* ga_W1 = (const float*)d_in[20]; const float* ga_b1 = (const float*)d_in[21];
  const float* ga1g = (const float*)d_in[22];  const float* ga1b = (const float*)d_in[23];
  const float* ga1m = (const float*)d_in[24];  const float* ga1v = (const float*)d_in[25];
  const float* ga_W2 = (const float*)d_in[26]; const float* ga_b2 = (const float*)d_in[27];
  const float* out_W0 = (const float*)d_in[28]; const float* out_b0 = (const float*)d_in[29];
  const float* out_W1 = (const float*)d_in[30]; const float* out_b1 = (const float*)d_in[31];
  const int* eidx  = (const int*)d_in[32];
  const int* row   = eidx;
  const int* col   = eidx + E;
  const int* batch = (const int*)d_in[33];

  float* ws = (float*)d_ws;
  size_t off = 0;
  auto alloc = [&](size_t n) { float* p = ws + off; off += (n + 63) & ~(size_t)63; return p; };
  float* x_cur  = alloc((size_t)N * D);                             // 7.7 MB
  unsigned short* ea_bf = (unsigned short*)alloc((size_t)E * 32);   // 61.4 MB bf16 [E][64]
  unsigned short* xWh   = (unsigned short*)alloc((size_t)N * 128);  // 15.4 MB bf16 [4][N][64]
  unsigned short* ZYperm= (unsigned short*)alloc((size_t)E * 64);   // 122.9 MB bf16 [pos][128]
  float* pi     = alloc((size_t)N * 4);
  float* pj     = alloc((size_t)N * 4);
  float* aArr   = alloc((size_t)E * 4);
  float* invA   = alloc((size_t)N * 4);
  float* out1   = alloc((size_t)N * 64);
  float* Bacc   = alloc((size_t)N * 256);
  float* AesT   = alloc(L * 256);
  float* WattT  = alloc(L * 512);
  float* a_un   = alloc(N);
  float* pooled = alloc((size_t)G * 64);
  int* start = (int*)alloc(N + 1);
  int* gstart = (int*)alloc(G + 1);
  int* eid_s = (int*)alloc(E);
  int* spos  = (int*)alloc(E);
  unsigned char* hs8 = (unsigned char*)alloc(E / 4 + 64);
  float* qsAll  = alloc((size_t)L * E * 4);                         // 38.4 MB
  // build-time scratch overlaid on xWh (first written in layer loop)
  int* deg = (int*)xWh;
  int* cur = deg + N;
  // post-loop overlays
  float* gcontrib = (float*)xWh;  // G*64 floats
  float* hbuf     = Bacc;         // N*64 floats

  hipMemsetAsync(deg, 0, (size_t)2 * N * sizeof(int), stream);
  hist_kernel<<<E / 256, 256, 0, stream>>>(row, deg);
  scan_kernel<<<1, 1024, 0, stream>>>(deg, start);
  fill_kernel<<<E / 256, 256, 0, stream>>>(row, start, cur, eid_s, spos);
  hs8_kernel<<<(E + 255) / 256, 256, 0, stream>>>(eid_s, hs8);
  gbound_kernel<<<(N + 255) / 256, 256, 0, stream>>>(batch, gstart);

  embed7_kernel<NF, false><<<960, 256, 0, stream>>>(x_in, node_W, node_b, x_cur, nullptr, N / 16);
  embed7_kernel<EF, true><<<1920, 256, 0, stream>>>(ea_in, edge_W, edge_b, nullptr, ea_bf, E / 16);

  aes_watt_all_kernel<<<L, 256, 0, stream>>>(conv_W, conv_att, AesT, WattT);
  qs3_kernel<<<L * QS_CPL, 256, 0, stream>>>(ea_bf, AesT, qsAll);

  for (int l = 0; l < L; l++) {
    const float* W = conv_W + (size_t)l * 128 * 256;
    xw_kernel<<<N / 16, 256, 0, stream>>>(x_cur, W, WattT + l * 512, xWh, pi, pj);
    score2_kernel<<<E / 256, 256, 0, stream>>>(qsAll + (size_t)l * E * 4, pi, pj, row, col,
                                               bn_g + l * H, bn_b + l * H,
                                               bn_m + l * H, bn_v + l * H, aArr);
    normsum_kernel<<<(N + 255) / 256, 256, 0, stream>>>(aArr, start, eid_s, invA);
    zyquad_kernel<<<EQ / 4, 256, 0, stream>>>(aArr, invA, ea_bf, xWh, row, col, spos, ZYperm);
    scatter3_kernel<<<N / 4, 256, 0, stream>>>(ZYperm, hs8, start, out1, Bacc);
    finish_kernel<<<N / 16, 256, 0, stream>>>(out1, Bacc, W, conv_bias + l * D, x_cur);
  }

  gacontrib_kernel<<<G / 16, 256, 0, stream>>>(gf, ga_W0, ga_b0, gcontrib);
  ga0_kernel<<<960, 256, 0, stream>>>(x_cur, gcontrib, batch, ga_W0,
                                      ga0g, ga0b, ga0m, ga0v, hbuf, N / 16);
  ga1_kernel<<<960, 256, 0, stream>>>(hbuf, ga_W1, ga_b1,
                                      ga1g, ga1b, ga1m, ga1v, ga_W2, ga_b2,
                                      a_un, N / 16);
  pool2_kernel<<<G, 256, 0, stream>>>(x_cur, a_un, gstart, pooled);
  final_kernel<<<G / 4, 256, 0, stream>>>(pooled, out_W0, out_b0, out_W1, out_b1,
                                          (float*)d_out);
}

// Round 15
// 1205.792 us; speedup vs baseline: 1.0237x; 1.0237x over previous
//
#include <hip/hip_runtime.h>

constexpr int N = 30000, E = 480000, G = 128, H = 4, D = 64;
constexpr int NF = 92, EF = 50, GF = 108, L = 5;
constexpr int EQ = E / 4;  // quads per head (120000); slot r -> head r/EQ, quad r%EQ
constexpr float EPS = 1e-3f;

__device__ __forceinline__ float lrelu(float t) { return t > 0.f ? t : 0.2f * t; }

// bf16 helpers (RTN-even), values are finite
__device__ __forceinline__ unsigned short f2bf(float f) {
  unsigned int u = __float_as_uint(f);
  u += 0x7FFFu + ((u >> 16) & 1u);
  return (unsigned short)(u >> 16);
}
__device__ __forceinline__ float bf2f(unsigned short s) {
  return __uint_as_float(((unsigned int)s) << 16);
}

// ---------------- CSR build: slots sorted by row ----------------
__global__ __launch_bounds__(256) void hist_kernel(const int* __restrict__ row,
                                                   int* __restrict__ deg) {
  int e = blockIdx.x * 256 + threadIdx.x;
  atomicAdd(&deg[row[e]], 1);
}

__global__ __launch_bounds__(1024) void scan_kernel(const int* __restrict__ deg,
                                                    int* __restrict__ start) {
  __shared__ int wsum[16];
  __shared__ int cbase;
  if (threadIdx.x == 0) cbase = 0;
  __syncthreads();
  int lane = threadIdx.x & 63, wave = threadIdx.x >> 6;
  for (int base = 0; base < N; base += 1024) {
    int i = base + (int)threadIdx.x;
    int v = (i < N) ? deg[i] : 0;
    int s = v;
#pragma unroll
    for (int off = 1; off < 64; off <<= 1) { int t = __shfl_up(s, off); if (lane >= off) s += t; }
    if (lane == 63) wsum[wave] = s;
    __syncthreads();
    if (wave == 0 && lane < 16) {
      int w = wsum[lane];
#pragma unroll
      for (int off = 1; off < 16; off <<= 1) { int t = __shfl_up(w, off); if (lane >= off) w += t; }
      wsum[lane] = w;
    }
    __syncthreads();
    int wbase = wave ? wsum[wave - 1] : 0;
    if (i < N) start[i] = cbase + wbase + (s - v);
    __syncthreads();
    if (threadIdx.x == 0) cbase += wsum[15];
    __syncthreads();
  }
  if (threadIdx.x == 0) start[N] = cbase;
}

__global__ __launch_bounds__(256) void fill_kernel(
    const int* __restrict__ row, const int* __restrict__ start, int* __restrict__ cur,
    int* __restrict__ eid_s) {
  int e = blockIdx.x * 256 + threadIdx.x;
  int r = row[e];
  int pos = start[r] + atomicAdd(&cur[r], 1);
  eid_s[pos] = e;
}

// ---------------- graph segment boundaries (batch is sorted) ------------------
__global__ __launch_bounds__(256) void gbound_kernel(const int* __restrict__ batch,
                                                     int* __restrict__ gstart) {
  int n = blockIdx.x * 256 + threadIdx.x;
  if (n >= N) return;
  int b = batch[n];
  int prev = (n == 0) ? -1 : batch[n - 1];
  for (int g = prev + 1; g <= b; g++) gstart[g] = n;
  if (n == N - 1) for (int g = b + 1; g <= G; g++) gstart[g] = N;
}

// ---------------- embedding, double-buffered LDS staging ----------------
template <int K, bool BF16OUT>
__global__ __launch_bounds__(256) void embed7_kernel(
    const float* __restrict__ in, const float* __restrict__ W,
    const float* __restrict__ bias, float* __restrict__ outF,
    unsigned short* __restrict__ outB, int ntiles) {
  constexpr int KP = (K + 3) & ~3;
  constexpr int NL = (16 * K + 255) / 256;
  __shared__ float xs[2][16][KP];
  int tid = threadIdx.x, lane = tid & 63, wave = tid >> 6;
  if (K != KP) {
    for (int f = tid; f < 2 * 16 * KP; f += 256)
      if (f % KP >= K) ((float*)xs)[f] = 0.f;
  }
  float wreg[KP];
#pragma unroll
  for (int k = 0; k < K; k++) wreg[k] = W[k * 64 + lane];
#pragma unroll
  for (int k = K; k < KP; k++) wreg[k] = 0.f;
  float bb = bias[lane];
  float stage[NL];
  int t = blockIdx.x;
  if (t < ntiles) {
#pragma unroll
    for (int i = 0; i < NL; i++) { int f = tid + i * 256; if (f < 16 * K) stage[i] = in[(size_t)t * 16 * K + f]; }
#pragma unroll
    for (int i = 0; i < NL; i++) { int f = tid + i * 256; if (f < 16 * K) xs[0][f / K][f % K] = stage[i]; }
  }
  __syncthreads();
  int cur = 0;
  for (; t < ntiles; t += gridDim.x) {
    int nxt = t + gridDim.x;
    if (nxt < ntiles) {
#pragma unroll
      for (int i = 0; i < NL; i++) { int f = tid + i * 256; if (f < 16 * K) stage[i] = in[(size_t)nxt * 16 * K + f]; }
    }
    float a0 = 0.f, a1 = 0.f, a2 = 0.f, a3 = 0.f;
#pragma unroll
    for (int kc = 0; kc < KP / 4; kc++) {
      float4 x0 = *(const float4*)&xs[cur][wave * 4 + 0][kc * 4];
      float4 x1 = *(const float4*)&xs[cur][wave * 4 + 1][kc * 4];
      float4 x2 = *(const float4*)&xs[cur][wave * 4 + 2][kc * 4];
      float4 x3 = *(const float4*)&xs[cur][wave * 4 + 3][kc * 4];
      float w0 = wreg[kc * 4], w1 = wreg[kc * 4 + 1], w2 = wreg[kc * 4 + 2], w3 = wreg[kc * 4 + 3];
      a0 = fmaf(x0.x, w0, fmaf(x0.y, w1, fmaf(x0.z, w2, fmaf(x0.w, w3, a0))));
      a1 = fmaf(x1.x, w0, fmaf(x1.y, w1, fmaf(x1.z, w2, fmaf(x1.w, w3, a1))));
      a2 = fmaf(x2.x, w0, fmaf(x2.y, w1, fmaf(x2.z, w2, fmaf(x2.w, w3, a2))));
      a3 = fmaf(x3.x, w0, fmaf(x3.y, w1, fmaf(x3.z, w2, fmaf(x3.w, w3, a3))));
    }
    size_t o = ((size_t)t * 16 + wave * 4) * 64 + lane;
    float r0 = lrelu(a0 + bb), r1 = lrelu(a1 + bb), r2 = lrelu(a2 + bb), r3 = lrelu(a3 + bb);
    if (BF16OUT) {
      outB[o] = f2bf(r0); outB[o + 64] = f2bf(r1);
      outB[o + 128] = f2bf(r2); outB[o + 192] = f2bf(r3);
    } else {
      outF[o] = r0; outF[o + 64] = r1; outF[o + 128] = r2; outF[o + 192] = r3;
    }
    if (nxt < ntiles) {
#pragma unroll
      for (int i = 0; i < NL; i++) { int f = tid + i * 256; if (f < 16 * K) xs[cur ^ 1][f / K][f % K] = stage[i]; }
    }
    __syncthreads();
    cur ^= 1;
  }
}

// ---------------- all-layer tiny precompute ----------------
__global__ __launch_bounds__(256) void aes_watt_all_kernel(
    const float* __restrict__ conv_W, const float* __restrict__ conv_att,
    float* __restrict__ AesT, float* __restrict__ WattT) {
  int l = blockIdx.x;
  const float* W = conv_W + (size_t)l * 128 * 256;
  const float* att = conv_att + (size_t)l * H * 128;
  int t = threadIdx.x;
  {
    int h = t >> 6, k = t & 63;
    float acc = 0.f;
    for (int d = 0; d < 64; d++)
      acc = fmaf(W[(64 + k) * 256 + h * 64 + d], att[h * 128 + d] + att[h * 128 + 64 + d], acc);
    AesT[l * 256 + h * 64 + k] = acc;
  }
  for (int idx = t; idx < 512; idx += 256) {
    int hh = idx >> 6, k = idx & 63;
    int h = hh >> 1, ij = hh & 1;
    float acc = 0.f;
    for (int d = 0; d < 64; d++)
      acc = fmaf(W[k * 256 + h * 64 + d], att[h * 128 + ij * 64 + d], acc);
    WattT[l * 512 + idx] = acc;
  }
}

// ---------------- qs3: block owns layer l; AesT in regs; stream edges --------
constexpr int QS_CPL = 960;  // chunks-per-layer stride
__global__ __launch_bounds__(256) void qs3_kernel(
    const unsigned short* __restrict__ ea, const float* __restrict__ AesT,
    float* __restrict__ qsAll) {
  int l = blockIdx.x / QS_CPL;
  int bx = blockIdx.x % QS_CPL;
  int tid = threadIdx.x;
  int k16 = tid & 3;
  float A[4][16];
#pragma unroll
  for (int h = 0; h < 4; h++) {
    const float* Ap = &AesT[l * 256 + h * 64 + k16 * 16];
#pragma unroll
    for (int j4 = 0; j4 < 4; j4++) {
      float4 v = ((const float4*)Ap)[j4];
      A[h][4 * j4] = v.x; A[h][4 * j4 + 1] = v.y;
      A[h][4 * j4 + 2] = v.z; A[h][4 * j4 + 3] = v.w;
    }
  }
  float* qOut = qsAll + (size_t)l * E * 4;
  for (int c = bx; c < E / 64; c += QS_CPL) {
    int e = c * 64 + (tid >> 2);
    const uint4* base = (const uint4*)&ea[(size_t)e * 64 + k16 * 16];
    uint4 ra = base[0], rb = base[1];
    float xv[16];
    {
      unsigned int uu[8] = {ra.x, ra.y, ra.z, ra.w, rb.x, rb.y, rb.z, rb.w};
#pragma unroll
      for (int i = 0; i < 8; i++) {
        xv[2 * i]     = __uint_as_float(uu[i] << 16);
        xv[2 * i + 1] = __uint_as_float(uu[i] & 0xFFFF0000u);
      }
    }
    float q0 = 0.f, q1 = 0.f, q2 = 0.f, q3 = 0.f;
#pragma unroll
    for (int j = 0; j < 16; j++) {
      float x = xv[j];
      q0 = fmaf(x, A[0][j], q0);
      q1 = fmaf(x, A[1][j], q1);
      q2 = fmaf(x, A[2][j], q2);
      q3 = fmaf(x, A[3][j], q3);
    }
    q0 += __shfl_xor(q0, 1); q1 += __shfl_xor(q1, 1);
    q2 += __shfl_xor(q2, 1); q3 += __shfl_xor(q3, 1);
    q0 += __shfl_xor(q0, 2); q1 += __shfl_xor(q1, 2);
    q2 += __shfl_xor(q2, 2); q3 += __shfl_xor(q3, 2);
    float qv = (k16 == 0) ? q0 : (k16 == 1) ? q1 : (k16 == 2) ? q2 : q3;
    qOut[(size_t)e * 4 + k16] = qv;
  }
}

// ---------------- xW = x@W[0:64,:] -> bf16 head-major [h][n][64]; + pi/pj -----
__global__ __launch_bounds__(256) void xw_kernel(
    const float* __restrict__ xc, const float* __restrict__ W, const float* __restrict__ WattT,
    unsigned short* __restrict__ xWh, float* __restrict__ pi, float* __restrict__ pj) {
  __shared__ float xs[16][64];
  __shared__ float wlT[8][68];
  int tid = threadIdx.x, blk = blockIdx.x, n0 = blk * 16;
  for (int f = tid; f < 1024; f += 256) xs[f >> 6][f & 63] = xc[(size_t)n0 * 64 + f];
  for (int f = tid; f < 512; f += 256) wlT[f >> 6][f & 63] = WattT[f];
  __syncthreads();
  float acc[16];
#pragma unroll
  for (int n = 0; n < 16; n++) acc[n] = 0.f;
#pragma unroll 4
  for (int kc = 0; kc < 16; kc++) {
    float w0 = W[(4 * kc + 0) * 256 + tid];
    float w1 = W[(4 * kc + 1) * 256 + tid];
    float w2 = W[(4 * kc + 2) * 256 + tid];
    float w3 = W[(4 * kc + 3) * 256 + tid];
#pragma unroll
    for (int n = 0; n < 16; n++) {
      float4 xv = *(const float4*)&xs[n][4 * kc];
      acc[n] = fmaf(xv.x, w0, fmaf(xv.y, w1, fmaf(xv.z, w2, fmaf(xv.w, w3, acc[n]))));
    }
  }
  int h = tid >> 6, dd = tid & 63;
#pragma unroll
  for (int n = 0; n < 16; n++)
    xWh[((size_t)h * N + (n0 + n)) * 64 + dd] = f2bf(acc[n]);
  if (tid < 128) {
    int n = tid >> 3, hh = tid & 7;
    float a = 0.f;
#pragma unroll
    for (int kc = 0; kc < 16; kc++) {
      float4 xv = *(const float4*)&xs[n][4 * kc];
      float4 wv = *(const float4*)&wlT[hh][4 * kc];
      a = fmaf(xv.x, wv.x, fmaf(xv.y, wv.y, fmaf(xv.z, wv.z, fmaf(xv.w, wv.w, a))));
    }
    int hq = hh >> 1, ij = hh & 1;
    float* dst = ij ? pj : pi;
    dst[(n0 + n) * 4 + hq] = a;
  }
}

// ---------------- edge scores: 1 thread/edge, reads precomputed qs ------------
__global__ __launch_bounds__(256) void score2_kernel(
    const float* __restrict__ qs, const float* __restrict__ pi, const float* __restrict__ pj,
    const int* __restrict__ row, const int* __restrict__ col,
    const float* __restrict__ bng, const float* __restrict__ bnb,
    const float* __restrict__ bnm, const float* __restrict__ bnv,
    float* __restrict__ aArr) {
  int e = blockIdx.x * 256 + threadIdx.x;
  int r = row[e], c = col[e];
  float4 q = ((const float4*)qs)[e];
  float4 piv = ((const float4*)pi)[r];
  float4 pjv = ((const float4*)pj)[c];
  float A0 = bng[0] * rsqrtf(bnv[0] + EPS), B0 = bnb[0] - bnm[0] * A0;
  float A1 = bng[1] * rsqrtf(bnv[1] + EPS), B1 = bnb[1] - bnm[1] * A1;
  float A2 = bng[2] * rsqrtf(bnv[2] + EPS), B2 = bnb[2] - bnm[2] * A2;
  float A3 = bng[3] * rsqrtf(bnv[3] + EPS), B3 = bnb[3] - bnm[3] * A3;
  float4 out;
  out.x = expf(lrelu(piv.x + pjv.x + q.x) * A0 + B0);
  out.y = expf(lrelu(piv.y + pjv.y + q.y) * A1 + B1);
  out.z = expf(lrelu(piv.z + pjv.z + q.z) * A2 + B2);
  out.w = expf(lrelu(piv.w + pjv.w + q.w) * A3 + B3);
  ((float4*)aArr)[e] = out;
}

// ---------------- softmax denom per (node,h) via CSR, no atomics --------------
__global__ __launch_bounds__(256) void normsum_kernel(
    const float* __restrict__ aArr, const int* __restrict__ start,
    const int* __restrict__ eid_s, float* __restrict__ inv) {
  int n = blockIdx.x * 256 + threadIdx.x;
  if (n >= N) return;
  int s0 = start[n], s1 = start[n + 1];
  float4 s = {0.f, 0.f, 0.f, 0.f};
  int p = s0;
  for (; p + 4 <= s1; p += 4) {
    int e0 = eid_s[p], e1 = eid_s[p + 1], e2 = eid_s[p + 2], e3 = eid_s[p + 3];
    float4 a0 = ((const float4*)aArr)[e0];
    float4 a1 = ((const float4*)aArr)[e1];
    float4 a2 = ((const float4*)aArr)[e2];
    float4 a3 = ((const float4*)aArr)[e3];
    s.x += (a0.x + a1.x) + (a2.x + a3.x);
    s.y += (a0.y + a1.y) + (a2.y + a3.y);
    s.z += (a0.z + a1.z) + (a2.z + a3.z);
    s.w += (a0.w + a1.w) + (a2.w + a3.w);
  }
  for (; p < s1; p++) {
    float4 a = ((const float4*)aArr)[eid_s[p]];
    s.x += a.x; s.y += a.y; s.z += a.z; s.w += a.w;
  }
  float4 iv;
  if (s1 > s0) { iv.x = 1.f / s.x; iv.y = 1.f / s.y; iv.z = 1.f / s.z; iv.w = 1.f / s.w; }
  else         { iv.x = iv.y = iv.z = iv.w = 0.f; }
  ((float4*)inv)[n] = iv;
}

// ---------------- zyquad: per quad q, all 4 heads; sequential ZY writes -------
// ZY[r][0..63] = Z row, ZY[r][64..127] = Y row (bf16), r = h*EQ + q
__global__ __launch_bounds__(256) void zyquad_kernel(
    const float* __restrict__ aArr, const float* __restrict__ invA,
    const unsigned short* __restrict__ ea, const unsigned short* __restrict__ xWh,
    const int* __restrict__ row, const int* __restrict__ col,
    unsigned short* __restrict__ ZYbf) {
  int q = blockIdx.x * 4 + (threadIdx.x >> 6);
  int lane = threadIdx.x & 63;
  const unsigned short* er = ea + (size_t)q * 256 + lane;
  float e0 = bf2f(er[0]), e1 = bf2f(er[64]), e2 = bf2f(er[128]), e3 = bf2f(er[192]);
  int4 rw = *(const int4*)&row[4 * q];
  int4 cl = *(const int4*)&col[4 * q];
  float4 A0 = ((const float4*)aArr)[4 * q + 0];
  float4 A1 = ((const float4*)aArr)[4 * q + 1];
  float4 A2 = ((const float4*)aArr)[4 * q + 2];
  float4 A3 = ((const float4*)aArr)[4 * q + 3];
  float4 I0 = ((const float4*)invA)[rw.x];
  float4 I1 = ((const float4*)invA)[rw.y];
  float4 I2 = ((const float4*)invA)[rw.z];
  float4 I3 = ((const float4*)invA)[rw.w];
  float c0[4] = {A0.x * I0.x, A0.y * I0.y, A0.z * I0.z, A0.w * I0.w};
  float c1[4] = {A1.x * I1.x, A1.y * I1.y, A1.z * I1.z, A1.w * I1.w};
  float c2[4] = {A2.x * I2.x, A2.y * I2.y, A2.z * I2.z, A2.w * I2.w};
  float c3[4] = {A3.x * I3.x, A3.y * I3.y, A3.z * I3.z, A3.w * I3.w};
#pragma unroll
  for (int h = 0; h < 4; h++) {
    const unsigned short* xw = xWh + (size_t)h * N * 64 + lane;
    float g0 = bf2f(xw[(size_t)cl.x * 64]);
    float g1 = bf2f(xw[(size_t)cl.y * 64]);
    float g2 = bf2f(xw[(size_t)cl.z * 64]);
    float g3 = bf2f(xw[(size_t)cl.w * 64]);
    float y = fmaf(c0[h], e0, fmaf(c1[h], e1, fmaf(c2[h], e2, c3[h] * e3)));
    float z = fmaf(c0[h], g0, fmaf(c1[h], g1, fmaf(c2[h], g2, c3[h] * g3)));
    size_t r = (size_t)h * EQ + q;
    ZYbf[r * 128 + lane] = f2bf(z);
    ZYbf[r * 128 + 64 + lane] = f2bf(y);
  }
}

// ---------------- scatter2: wave per node, 8-deep pipelined row reads ---------
__global__ __launch_bounds__(256) void scatter2_kernel(
    const unsigned short* __restrict__ ZYbf,
    const int* __restrict__ start, const int* __restrict__ eid_s,
    float* __restrict__ out1, float* __restrict__ Bacc) {
  int wave = threadIdx.x >> 6, lane = threadIdx.x & 63;
  int n = blockIdx.x * 4 + wave;
  int s0 = __builtin_amdgcn_readfirstlane(start[n]);
  int s1 = __builtin_amdgcn_readfirstlane(start[n + 1]);
  float m = 0.f;
  float b0 = 0.f, b1 = 0.f, b2 = 0.f, b3 = 0.f;
  int p = s0;
  for (; p + 8 <= s1; p += 8) {
    int r[8];
#pragma unroll
    for (int i = 0; i < 8; i++) r[i] = eid_s[p + i];
    float z[8], y[8];
#pragma unroll
    for (int i = 0; i < 8; i++) {
      z[i] = bf2f(ZYbf[(size_t)r[i] * 128 + lane]);
      y[i] = bf2f(ZYbf[(size_t)r[i] * 128 + 64 + lane]);
    }
#pragma unroll
    for (int i = 0; i < 8; i++) {
      m += z[i];
      int h = r[i] / EQ;
      if (h == 0) b0 += y[i]; else if (h == 1) b1 += y[i];
      else if (h == 2) b2 += y[i]; else b3 += y[i];
    }
  }
  for (; p < s1; p++) {
    int r = eid_s[p];
    float z = bf2f(ZYbf[(size_t)r * 128 + lane]);
    float y = bf2f(ZYbf[(size_t)r * 128 + 64 + lane]);
    m += z;
    int h = r / EQ;
    if (h == 0) b0 += y; else if (h == 1) b1 += y; else if (h == 2) b2 += y; else b3 += y;
  }
  out1[(size_t)n * 64 + lane] = m;
  float* Bn = Bacc + (size_t)n * 256 + lane;
  Bn[0] = b0; Bn[64] = b1; Bn[128] = b2; Bn[192] = b3;
}

// ---------------- finish: x += bias + 0.25*(out1 + B@W_e) ----------------
__global__ __launch_bounds__(256) void finish_kernel(
    const float* __restrict__ out1, const float* __restrict__ Bacc,
    const float* __restrict__ W, const float* __restrict__ bias, float* __restrict__ xc) {
  __shared__ float Bl[16][256];
  int tid = threadIdx.x, blk = blockIdx.x;
  for (int f = tid; f < 4096; f += 256) Bl[f >> 8][f & 255] = Bacc[(size_t)blk * 4096 + f];
  __syncthreads();
  int lane = tid & 63, wave = tid >> 6;
  float a0 = 0.f, a1 = 0.f, a2 = 0.f, a3 = 0.f;
#pragma unroll
  for (int h = 0; h < 4; h++) {
#pragma unroll 4
    for (int kc = 0; kc < 16; kc++) {
      float w0 = W[(64 + 4 * kc + 0) * 256 + h * 64 + lane];
      float w1 = W[(64 + 4 * kc + 1) * 256 + h * 64 + lane];
      float w2 = W[(64 + 4 * kc + 2) * 256 + h * 64 + lane];
      float w3 = W[(64 + 4 * kc + 3) * 256 + h * 64 + lane];
      float4 b0v = *(const float4*)&Bl[wave * 4 + 0][h * 64 + 4 * kc];
      float4 b1v = *(const float4*)&Bl[wave * 4 + 1][h * 64 + 4 * kc];
      float4 b2v = *(const float4*)&Bl[wave * 4 + 2][h * 64 + 4 * kc];
      float4 b3v = *(const float4*)&Bl[wave * 4 + 3][h * 64 + 4 * kc];
      a0 = fmaf(b0v.x, w0, fmaf(b0v.y, w1, fmaf(b0v.z, w2, fmaf(b0v.w, w3, a0))));
      a1 = fmaf(b1v.x, w0, fmaf(b1v.y, w1, fmaf(b1v.z, w2, fmaf(b1v.w, w3, a1))));
      a2 = fmaf(b2v.x, w0, fmaf(b2v.y, w1, fmaf(b2v.z, w2, fmaf(b2v.w, w3, a2))));
      a3 = fmaf(b3v.x, w0, fmaf(b3v.y, w1, fmaf(b3v.z, w2, fmaf(b3v.w, w3, a3))));
    }
  }
  float bb = bias[lane];
  size_t i0 = (size_t)(blk * 16 + wave * 4) * 64 + lane;
  xc[i0]       += bb + 0.25f * (out1[i0] + a0);
  xc[i0 + 64]  += bb + 0.25f * (out1[i0 + 64] + a1);
  xc[i0 + 128] += bb + 0.25f * (out1[i0 + 128] + a2);
  xc[i0 + 192] += bb + 0.25f * (out1[i0 + 192] + a3);
}

// ---------------- global attention, stage 0 precompute ----------------
__global__ __launch_bounds__(256) void gacontrib_kernel(
    const float* __restrict__ gfeat, const float* __restrict__ W0,
    const float* __restrict__ b0, float* __restrict__ gc) {
  __shared__ float gs[16][GF];
  int tid = threadIdx.x, blk = blockIdx.x;
  int lane = tid & 63, wave = tid >> 6;
  for (int f = tid; f < 16 * GF; f += 256) gs[f / GF][f % GF] = gfeat[(size_t)blk * 16 * GF + f];
  float wreg[GF];
#pragma unroll
  for (int k = 0; k < GF; k++) wreg[k] = W0[(64 + k) * 64 + lane];
  __syncthreads();
  float a0 = 0.f, a1 = 0.f, a2 = 0.f, a3 = 0.f;
#pragma unroll
  for (int kc = 0; kc < GF / 4; kc++) {
    float4 x0 = *(const float4*)&gs[wave * 4 + 0][kc * 4];
    float4 x1 = *(const float4*)&gs[wave * 4 + 1][kc * 4];
    float4 x2 = *(const float4*)&gs[wave * 4 + 2][kc * 4];
    float4 x3 = *(const float4*)&gs[wave * 4 + 3][kc * 4];
    float w0 = wreg[kc * 4], w1 = wreg[kc * 4 + 1], w2 = wreg[kc * 4 + 2], w3 = wreg[kc * 4 + 3];
    a0 = fmaf(x0.x, w0, fmaf(x0.y, w1, fmaf(x0.z, w2, fmaf(x0.w, w3, a0))));
    a1 = fmaf(x1.x, w0, fmaf(x1.y, w1, fmaf(x1.z, w2, fmaf(x1.w, w3, a1))));
    a2 = fmaf(x2.x, w0, fmaf(x2.y, w1, fmaf(x2.z, w2, fmaf(x2.w, w3, a2))));
    a3 = fmaf(x3.x, w0, fmaf(x3.y, w1, fmaf(x3.z, w2, fmaf(x3.w, w3, a3))));
  }
  float bb = b0[lane];
  size_t o = ((size_t)blk * 16 + wave * 4) * 64 + lane;
  gc[o]       = a0 + bb;
  gc[o + 64]  = a1 + bb;
  gc[o + 128] = a2 + bb;
  gc[o + 192] = a3 + bb;
}

// ---------------- ga stage 1 ----------------
__global__ __launch_bounds__(256) void ga0_kernel(
    const float* __restrict__ xc, const float* __restrict__ gc, const int* __restrict__ batch,
    const float* __restrict__ W0,
    const float* __restrict__ g0, const float* __restrict__ bb0,
    const float* __restrict__ m0, const float* __restrict__ v0,
    float* __restrict__ hout, int ntiles) {
  __shared__ float xs[16][64];
  __shared__ int bl[16];
  int tid = threadIdx.x, lane = tid & 63, wave = tid >> 6;
  float wreg[64];
#pragma unroll
  for (int k = 0; k < 64; k++) wreg[k] = W0[k * 64 + lane];
  float sc = rsqrtf(v0[lane] + EPS) * g0[lane];
  float mm = m0[lane], be = bb0[lane];
  for (int t = blockIdx.x; t < ntiles; t += gridDim.x) {
    __syncthreads();
    if (tid < 16) bl[tid] = batch[t * 16 + tid];
    for (int f = tid; f < 1024; f += 256) xs[f >> 6][f & 63] = xc[(size_t)t * 1024 + f];
    __syncthreads();
    float a0 = 0.f, a1 = 0.f, a2 = 0.f, a3 = 0.f;
#pragma unroll
    for (int kc = 0; kc < 16; kc++) {
      float4 x0 = *(const float4*)&xs[wave * 4 + 0][kc * 4];
      float4 x1 = *(const float4*)&xs[wave * 4 + 1][kc * 4];
      float4 x2 = *(const float4*)&xs[wave * 4 + 2][kc * 4];
      float4 x3 = *(const float4*)&xs[wave * 4 + 3][kc * 4];
      float w0 = wreg[kc * 4], w1 = wreg[kc * 4 + 1], w2 = wreg[kc * 4 + 2], w3 = wreg[kc * 4 + 3];
      a0 = fmaf(x0.x, w0, fmaf(x0.y, w1, fmaf(x0.z, w2, fmaf(x0.w, w3, a0))));
      a1 = fmaf(x1.x, w0, fmaf(x1.y, w1, fmaf(x1.z, w2, fmaf(x1.w, w3, a1))));
      a2 = fmaf(x2.x, w0, fmaf(x2.y, w1, fmaf(x2.z, w2, fmaf(x2.w, w3, a2))));
      a3 = fmaf(x3.x, w0, fmaf(x3.y, w1, fmaf(x3.z, w2, fmaf(x3.w, w3, a3))));
    }
    a0 += gc[(size_t)bl[wave * 4 + 0] * 64 + lane];
    a1 += gc[(size_t)bl[wave * 4 + 1] * 64 + lane];
    a2 += gc[(size_t)bl[wave * 4 + 2] * 64 + lane];
    a3 += gc[(size_t)bl[wave * 4 + 3] * 64 + lane];
    size_t o = ((size_t)t * 16 + wave * 4) * 64 + lane;
    hout[o]       = fmaxf((a0 - mm) * sc + be, 0.f);
    hout[o + 64]  = fmaxf((a1 - mm) * sc + be, 0.f);
    hout[o + 128] = fmaxf((a2 - mm) * sc + be, 0.f);
    hout[o + 192] = fmaxf((a3 - mm) * sc + be, 0.f);
  }
}

// ---------------- ga stage 2: a_un only, NO atomics ----------------
__global__ __launch_bounds__(256) void ga1_kernel(
    const float* __restrict__ hbuf,
    const float* __restrict__ W1, const float* __restrict__ b1,
    const float* __restrict__ g1, const float* __restrict__ bb1,
    const float* __restrict__ m1, const float* __restrict__ v1,
    const float* __restrict__ W2, const float* __restrict__ b2,
    float* __restrict__ a_un, int ntiles) {
  __shared__ float hsh[16][64];
  int tid = threadIdx.x, lane = tid & 63, wave = tid >> 6;
  float wreg[64];
#pragma unroll
  for (int k = 0; k < 64; k++) wreg[k] = W1[k * 64 + lane];
  float sc1 = rsqrtf(v1[lane] + EPS) * g1[lane];
  float mm1 = m1[lane], be1 = bb1[lane], bb1v = b1[lane];
  float w2v = W2[lane], b2v = b2[0];
  for (int t = blockIdx.x; t < ntiles; t += gridDim.x) {
    __syncthreads();
    for (int f = tid; f < 1024; f += 256) hsh[f >> 6][f & 63] = hbuf[(size_t)t * 1024 + f];
    __syncthreads();
    float c0 = 0.f, c1 = 0.f, c2 = 0.f, c3 = 0.f;
#pragma unroll
    for (int kc = 0; kc < 16; kc++) {
      float4 x0 = *(const float4*)&hsh[wave * 4 + 0][kc * 4];
      float4 x1 = *(const float4*)&hsh[wave * 4 + 1][kc * 4];
      float4 x2 = *(const float4*)&hsh[wave * 4 + 2][kc * 4];
      float4 x3 = *(const float4*)&hsh[wave * 4 + 3][kc * 4];
      float w0 = wreg[kc * 4], w1 = wreg[kc * 4 + 1], w2 = wreg[kc * 4 + 2], w3 = wreg[kc * 4 + 3];
      c0 = fmaf(x0.x, w0, fmaf(x0.y, w1, fmaf(x0.z, w2, fmaf(x0.w, w3, c0))));
      c1 = fmaf(x1.x, w0, fmaf(x1.y, w1, fmaf(x1.z, w2, fmaf(x1.w, w3, c1))));
      c2 = fmaf(x2.x, w0, fmaf(x2.y, w1, fmaf(x2.z, w2, fmaf(x2.w, w3, c2))));
      c3 = fmaf(x3.x, w0, fmaf(x3.y, w1, fmaf(x3.z, w2, fmaf(x3.w, w3, c3))));
    }
    float p0 = fmaxf((c0 + bb1v - mm1) * sc1 + be1, 0.f) * w2v;
    float p1 = fmaxf((c1 + bb1v - mm1) * sc1 + be1, 0.f) * w2v;
    float p2 = fmaxf((c2 + bb1v - mm1) * sc1 + be1, 0.f) * w2v;
    float p3 = fmaxf((c3 + bb1v - mm1) * sc1 + be1, 0.f) * w2v;
#pragma unroll
    for (int off = 1; off < 64; off <<= 1) {
      p0 += __shfl_xor(p0, off); p1 += __shfl_xor(p1, off);
      p2 += __shfl_xor(p2, off); p3 += __shfl_xor(p3, off);
    }
    if (lane < 4) {
      float pv = (lane == 0) ? p0 : (lane == 1) ? p1 : (lane == 2) ? p2 : p3;
      a_un[t * 16 + wave * 4 + lane] = expf(pv + b2v);
    }
  }
}

// ---------------- pool2: block per graph, segment reduce, no atomics ----------
__global__ __launch_bounds__(256) void pool2_kernel(
    const float* __restrict__ xc, const float* __restrict__ a_un,
    const int* __restrict__ gstart, float* __restrict__ pooled) {
  __shared__ float red[4][64];
  __shared__ float s_norm;
  int g = blockIdx.x;
  int tid = threadIdx.x, lane = tid & 63, wave = tid >> 6;
  int s0 = gstart[g], s1 = gstart[g + 1];
  float ns = 0.f;
  for (int n = s0 + tid; n < s1; n += 256) ns += a_un[n];
#pragma unroll
  for (int off = 1; off < 64; off <<= 1) ns += __shfl_xor(ns, off);
  if (lane == 0) red[wave][0] = ns;
  __syncthreads();
  if (tid == 0) s_norm = (red[0][0] + red[1][0]) + (red[2][0] + red[3][0]);
  __syncthreads();
  float inv = (s1 > s0) ? 1.f / s_norm : 0.f;
  __syncthreads();
  float acc = 0.f;
  for (int n = s0 + wave; n < s1; n += 4)
    acc = fmaf(xc[(size_t)n * 64 + lane], a_un[n], acc);
  red[wave][lane] = acc;
  __syncthreads();
  if (wave == 0)
    pooled[(size_t)g * 64 + lane] =
        inv * ((red[0][lane] + red[1][lane]) + (red[2][lane] + red[3][lane]));
}

__global__ __launch_bounds__(256) void final_kernel(
    const float* __restrict__ pooled, const float* __restrict__ W0,
    const float* __restrict__ b0, const float* __restrict__ W1,
    const float* __restrict__ b1, float* __restrict__ out) {
  int g = blockIdx.x * 4 + (threadIdx.x >> 6);
  int d = threadIdx.x & 63;
  float pv = pooled[g * 64 + d];
  float acc = b0[d];
  for (int k = 0; k < 64; k++) acc = fmaf(__shfl(pv, k), W0[k * 64 + d], acc);
  acc = fmaxf(acc, 0.f);
  float p = acc * W1[d];
  for (int off = 1; off < 64; off <<= 1) p += __shfl_xor(p, off);
  if (d == 0) out[g] = p + b1[0];
}

extern "C" void kernel_launch(void* const* d_in, const int* in_sizes, int n_in,
                              void* d_out, int out_size, void* d_ws, size_t ws_size,
                              hipStream_t stream) {
  (void)in_sizes; (void)n_in; (void)out_size; (void)ws_size;
  const float* x_in    = (const float*)d_in[0];
  const float* ea_in   = (const float*)d_in[1];
  const float* gf      = (const float*)d_in[2];
  const float* node_W  = (const float*)d_in[3];
  const float* node_b  = (const float*)d_in[4];
  const float* edge_W  = (const float*)d_in[5];
  const float* edge_b  = (const float*)d_in[6];
  const float* conv_W  = (const float*)d_in[7];
  const float* conv_att= (const float*)d_in[8];
  const float* conv_bias=(const float*)d_in[9];
  const float* bn_g = (const float*)d_in[10];
  const float* bn_b = (const float*)d_in[11];
  const float* bn_m = (const float*)d_in[12];
  const float* bn_v = (const float*)d_in[13];
  const float* ga_W0 = (const float*)d_in[14]; const float* ga_b0 = (const float*)d_in[15];
  const float* ga0g = (const float*)d_in[16];  const float* ga0b = (const float*)d_in[17];
  const float* ga0m = (const float*)d_in[18];  const float* ga0v = (const float*)d_in[19];
  const float* ga_W1 = (const float*)d_in[20]; const float* ga_b1 = (const float*)d_in[21];
  const float* ga1g = (const float*)d_in[22];  const float* ga1b = (const float*)d_in[23];
  const float* ga1m = (const float*)d_in[24];  const float* ga1v = (const float*)d_in[25];
  const float* ga_W2 = (const float*)d_in[26]; const float* ga_b2 = (const float*)d_in[27];
  const float* out_W0 = (const float*)d_in[28]; const float* out_b0 = (const float*)d_in[29];
  const float* out_W1 = (const float*)d_in[30]; const float* out_b1 = (const float*)d_in[31];
  const int* eidx  = (const int*)d_in[32];
  const int* row   = eidx;
  const int* col   = eidx + E;
  const int* batch = (const int*)d_in[33];

  float* ws = (float*)d_ws;
  size_t off = 0;
  auto alloc = [&](size_t n) { float* p = ws + off; off += (n + 63) & ~(size_t)63; return p; };
  float* x_cur  = alloc((size_t)N * D);                             // 7.7 MB
  unsigned short* ea_bf = (unsigned short*)alloc((size_t)E * 32);   // 61.4 MB bf16 [E][64]
  unsigned short* xWh   = (unsigned short*)alloc((size_t)N * 128);  // 15.4 MB bf16 [4][N][64]
  unsigned short* ZYbf  = (unsigned short*)alloc((size_t)E * 64);   // 122.9 MB bf16 [slot][128]
  float* pi     = alloc((size_t)N * 4);
  float* pj     = alloc((size_t)N * 4);
  float* aArr   = alloc((size_t)E * 4);
  float* invA   = alloc((size_t)N * 4);
  float* out1   = alloc((size_t)N * 64);
  float* Bacc   = alloc((size_t)N * 256);
  float* AesT   = alloc(L * 256);
  float* WattT  = alloc(L * 512);
  float* a_un   = alloc(N);
  float* pooled = alloc((size_t)G * 64);
  int* start = (int*)alloc(N + 1);
  int* gstart = (int*)alloc(G + 1);
  int* eid_s = (int*)alloc(E);
  float* qsAll  = alloc((size_t)L * E * 4);                         // 38.4 MB
  // build-time scratch overlaid on xWh (first written in layer loop)
  int* deg = (int*)xWh;
  int* cur = deg + N;
  // post-loop overlays
  float* gcontrib = (float*)xWh;  // G*64 floats
  float* hbuf     = Bacc;         // N*64 floats

  hipMemsetAsync(deg, 0, (size_t)2 * N * sizeof(int), stream);
  hist_kernel<<<E / 256, 256, 0, stream>>>(row, deg);
  scan_kernel<<<1, 1024, 0, stream>>>(deg, start);
  fill_kernel<<<E / 256, 256, 0, stream>>>(row, start, cur, eid_s);
  gbound_kernel<<<(N + 255) / 256, 256, 0, stream>>>(batch, gstart);

  embed7_kernel<NF, false><<<960, 256, 0, stream>>>(x_in, node_W, node_b, x_cur, nullptr, N / 16);
  embed7_kernel<EF, true><<<1920, 256, 0, stream>>>(ea_in, edge_W, edge_b, nullptr, ea_bf, E / 16);

  aes_watt_all_kernel<<<L, 256, 0, stream>>>(conv_W, conv_att, AesT, WattT);
  qs3_kernel<<<L * QS_CPL, 256, 0, stream>>>(ea_bf, AesT, qsAll);

  for (int l = 0; l < L; l++) {
    const float* W = conv_W + (size_t)l * 128 * 256;
    xw_kernel<<<N / 16, 256, 0, stream>>>(x_cur, W, WattT + l * 512, xWh, pi, pj);
    score2_kernel<<<E / 256, 256, 0, stream>>>(qsAll + (size_t)l * E * 4, pi, pj, row, col,
                                               bn_g + l * H, bn_b + l * H,
                                               bn_m + l * H, bn_v + l * H, aArr);
    normsum_kernel<<<(N + 255) / 256, 256, 0, stream>>>(aArr, start, eid_s, invA);
    zyquad_kernel<<<EQ / 4, 256, 0, stream>>>(aArr, invA, ea_bf, xWh, row, col, ZYbf);
    scatter2_kernel<<<N / 4, 256, 0, stream>>>(ZYbf, start, eid_s, out1, Bacc);
    finish_kernel<<<N / 16, 256, 0, stream>>>(out1, Bacc, W, conv_bias + l * D, x_cur);
  }

  gacontrib_kernel<<<G / 16, 256, 0, stream>>>(gf, ga_W0, ga_b0, gcontrib);
  ga0_kernel<<<960, 256, 0, stream>>>(x_cur, gcontrib, batch, ga_W0,
                                      ga0g, ga0b, ga0m, ga0v, hbuf, N / 16);
  ga1_kernel<<<960, 256, 0, stream>>>(hbuf, ga_W1, ga_b1,
                                      ga1g, ga1b, ga1m, ga1v, ga_W2, ga_b2,
                                      a_un, N / 16);
  pool2_kernel<<<G, 256, 0, stream>>>(x_cur, a_un, gstart, pooled);
  final_kernel<<<G / 4, 256, 0, stream>>>(pooled, out_W0, out_b0, out_W1, out_b1,
                                          (float*)d_out);
}